// Round 9
// baseline (248.937 us; speedup 1.0000x reference)
//
#include <hip/hip_runtime.h>

#define N_TOT 65536
#define C_DIM 128
#define K_CB  1024
#define BN 64
#define BT 64
#define NTILE (K_CB / BT)
#define NROW_B 4
#define NBLK_B (N_TOT / NROW_B)

typedef __attribute__((ext_vector_type(8))) short bf16x8;   // 8 bf16 = 4 VGPR
typedef __attribute__((ext_vector_type(4))) float f32x4;

__device__ __forceinline__ ushort f2bf_rne(float f) {
  unsigned u = __float_as_uint(f);
  return (ushort)((u + 0x7FFFu + ((u >> 16) & 1u)) >> 16);
}
__device__ __forceinline__ unsigned med3u(unsigned a, unsigned b, unsigned c) {
  // max(min(a,b), min(max(a,b),c)) == median -> LLVM folds to v_med3_u32
  return max(min(a, b), min(max(a, b), c));
}

// ---------------------------------------------------------------------------
// Prep (fused): blocks 0..63 shuffle codebook into MFMA-fragment order
//   cbs[((g*4+ks)*64 + lane)*8 + j] = bf16(cb[g*16 + (lane&15)][ks*32+(lane>>4)*8+j])
// so dist's per-wave frag load is 64 lanes x 16 B CONTIGUOUS (1 KB segment).
// Blocks 64..67: cb_sq fp64 row sums -> cbsq (exact) + cbsqb (= cbsq+192 bias).
// ---------------------------------------------------------------------------
__global__ __launch_bounds__(256) void prep_kernel(const float* __restrict__ cb,
                                                   ushort* __restrict__ cbs,
                                                   float* __restrict__ cbsq,
                                                   float* __restrict__ cbsqb) {
  int b = blockIdx.x;
  if (b < 64) {
    int id = b * 256 + threadIdx.x;        // 0..16383 = (g, ks, lane)
    int g = id >> 8, rem = id & 255;
    int ks = rem >> 6, lane = rem & 63;
    int row = g * 16 + (lane & 15);
    int col = ks * 32 + (lane >> 4) * 8;
    const float4* src = reinterpret_cast<const float4*>(cb + (size_t)row * C_DIM + col);
    float4 a = src[0], c = src[1];
    ushort h[8] = {f2bf_rne(a.x), f2bf_rne(a.y), f2bf_rne(a.z), f2bf_rne(a.w),
                   f2bf_rne(c.x), f2bf_rne(c.y), f2bf_rne(c.z), f2bf_rne(c.w)};
    reinterpret_cast<uint4*>(cbs)[id] = *reinterpret_cast<const uint4*>(h);
  } else {
    int w = threadIdx.x >> 6, lane = threadIdx.x & 63;
    int base = (b - 64) * 256 + w * 64;
    for (int i = 0; i < 64; ++i) {
      int r = base + i;
      float2 v = reinterpret_cast<const float2*>(cb + (size_t)r * C_DIM)[lane];
      double s = (double)v.x * (double)v.x + (double)v.y * (double)v.y;
#pragma unroll
      for (int off = 32; off >= 1; off >>= 1) s += __shfl_xor(s, off, 64);
      if (lane == 0) { cbsq[r] = (float)s; cbsqb[r] = (float)s + 192.0f; }
    }
  }
}

// ---------------------------------------------------------------------------
// MFMA filter, barrier-free K-loop, coalesced frag loads from shuffled cbs.
// key' = (cbsq[k]+192) - 2*dot in [183,201] -> positive-float bits uint-
// monotone; packed = (bits & ~1023) | code; per-lane top-3 via min+2*med3.
// Per-row pool 96 -> top-8 -> cand. (R8-verified containment margins.)
// ---------------------------------------------------------------------------
__global__ __launch_bounds__(256, 3) void dist_mfma_kernel(
    const float* __restrict__ ze, const ushort* __restrict__ cbs,
    const float* __restrict__ cbsqb, ushort* __restrict__ cand) {
  __shared__ __align__(16) char smem[24832];              // max(z 16384, pool 24832)
  ushort* zhS = reinterpret_cast<ushort*>(smem);          // [64][128] xor-swizzled
  unsigned* pool = reinterpret_cast<unsigned*>(smem);     // [64][97]

  const int tid = threadIdx.x;
  const int w = tid >> 6, lane = tid & 63;
  const int mh = w & 1, nh = w >> 1;
  const int c16 = lane & 15, quad = lane >> 4;
  const int rowbase = blockIdx.x * BN;

  // Stage z tile -> bf16 LDS (once).
#pragma unroll
  for (int p = 0; p < 4; ++p) {
    int fid = p * 256 + tid;
    int row = fid >> 4, c8 = fid & 15;
    float4 a = reinterpret_cast<const float4*>(ze)[(size_t)(rowbase + row) * 32 + c8 * 2];
    float4 b = reinterpret_cast<const float4*>(ze)[(size_t)(rowbase + row) * 32 + c8 * 2 + 1];
    ushort h[8] = {f2bf_rne(a.x), f2bf_rne(a.y), f2bf_rne(a.z), f2bf_rne(a.w),
                   f2bf_rne(b.x), f2bf_rne(b.y), f2bf_rne(b.z), f2bf_rne(b.w)};
    *reinterpret_cast<uint4*>(&zhS[row * 128 + ((c8 ^ (row & 7)) * 8)]) =
        *reinterpret_cast<const uint4*>(h);
  }
  __syncthreads();

  // Hoist A-frags to regs; zhS dead after.
  const int xk = c16 & 7;
  bf16x8 afrag[2][4];
#pragma unroll
  for (int m2 = 0; m2 < 2; ++m2) {
    int r = (mh * 32 + m2 * 16 + c16) * 128;
#pragma unroll
    for (int ks = 0; ks < 4; ++ks)
      afrag[m2][ks] = *reinterpret_cast<const bf16x8*>(&zhS[r + ((ks * 4 + quad) ^ xk) * 8]);
  }
  __syncthreads();   // pool aliasing safe

  unsigned t3[8][3];
#pragma unroll
  for (int s = 0; s < 8; ++s) { t3[s][0] = 0xFFFFFFFFu; t3[s][1] = 0xFFFFFFFFu; t3[s][2] = 0xFFFFFFFFu; }

  // Frag-ordered B: unit (g*4+ks) is 512 ushorts; per-wave lane*8 contiguous.
  const ushort* bbase = cbs + (size_t)(nh * 8 + 0) * 512 + lane * 8;   // n2=0,ks=0 of this nh

  for (int t = 0; t < NTILE; ++t) {
    bf16x8 bf[2][4];
#pragma unroll
    for (int n2 = 0; n2 < 2; ++n2)
#pragma unroll
      for (int ks = 0; ks < 4; ++ks)
        bf[n2][ks] = *reinterpret_cast<const bf16x8*>(bbase + t * 8192 + n2 * 2048 + ks * 512);

    f32x4 acc[2][2];
#pragma unroll
    for (int m2 = 0; m2 < 2; ++m2)
#pragma unroll
      for (int n2 = 0; n2 < 2; ++n2) acc[m2][n2] = (f32x4){0.f, 0.f, 0.f, 0.f};

#pragma unroll
    for (int ks = 0; ks < 4; ++ks)
#pragma unroll
      for (int m2 = 0; m2 < 2; ++m2)
#pragma unroll
        for (int n2 = 0; n2 < 2; ++n2)
          acc[m2][n2] = __builtin_amdgcn_mfma_f32_16x16x32_bf16(afrag[m2][ks], bf[n2][ks], acc[m2][n2], 0, 0, 0);

    // keys + packed top-3 (min + 2x med3). D layout: col=lane&15, row=quad*4+reg.
#pragma unroll
    for (int n2 = 0; n2 < 2; ++n2) {
      int code = t * BT + nh * 32 + n2 * 16 + c16;
      float csb = cbsqb[code];
#pragma unroll
      for (int m2 = 0; m2 < 2; ++m2)
#pragma unroll
        for (int reg = 0; reg < 4; ++reg) {
          float kf = fmaf(-2.f, acc[m2][n2][reg], csb);
          unsigned pk = (__float_as_uint(kf) & 0xFFFFFC00u) | (unsigned)code;
          int s = m2 * 4 + reg;
          unsigned o0 = t3[s][0], o1 = t3[s][1], o2 = t3[s][2];
          t3[s][0] = min(o0, pk);
          t3[s][1] = med3u(o0, o1, pk);
          t3[s][2] = med3u(o1, o2, pk);
        }
    }
  }

  // Pool: 32 (nh,c16) groups x top-3 = 96 packed keys per row (stride 97).
#pragma unroll
  for (int s = 0; s < 8; ++s) {
    int row = mh * 32 + (s >> 2) * 16 + quad * 4 + (s & 3);
    int col = (nh * 16 + c16) * 3;
    pool[row * 97 + col] = t3[s][0];
    pool[row * 97 + col + 1] = t3[s][1];
    pool[row * 97 + col + 2] = t3[s][2];
  }
  __syncthreads();
  if (tid < BN) {
    unsigned k[8];
#pragma unroll
    for (int q = 0; q < 8; ++q) k[q] = 0xFFFFFFFFu;
    for (int p = 0; p < 96; ++p) {
      unsigned v = pool[tid * 97 + p];
      if (v < k[7]) {
        k[7] = v;
#pragma unroll
        for (int q = 7; q > 0; --q)
          if (k[q] < k[q - 1]) { unsigned tk = k[q]; k[q] = k[q - 1]; k[q - 1] = tk; }
      }
    }
    uint4 cw;
    cw.x = (k[0] & 1023u) | ((k[1] & 1023u) << 16);
    cw.y = (k[2] & 1023u) | ((k[3] & 1023u) << 16);
    cw.z = (k[4] & 1023u) | ((k[5] & 1023u) << 16);
    cw.w = (k[6] & 1023u) | ((k[7] & 1023u) << 16);
    reinterpret_cast<uint4*>(cand)[rowbase + tid] = cw;
  }
}

// ---------------------------------------------------------------------------
// Rescore (R3-verified arithmetic, serial-candidate form — z read ONCE):
//   key = fl32( fl32( zs - fl32(2*cross_fp64) ) + cb_sq32 ), tie -> low idx.
// R8's group-split read each z row 8x (~256 MB redundant) — reverted.
// ---------------------------------------------------------------------------
__global__ __launch_bounds__(256) void rescore_kernel(
    const float* __restrict__ ze, const float* __restrict__ cb,
    const float* __restrict__ cbsq, const ushort* __restrict__ cand,
    float* __restrict__ zq, float* __restrict__ idx_f,
    double* __restrict__ partial) {
  int w = threadIdx.x >> 6, lane = threadIdx.x & 63;
  int row = blockIdx.x * NROW_B + w;

  float2 z = reinterpret_cast<const float2*>(ze)[(size_t)row * 64 + lane];
  double zsum = (double)z.x * (double)z.x + (double)z.y * (double)z.y;
#pragma unroll
  for (int off = 32; off >= 1; off >>= 1) zsum += __shfl_xor(zsum, off, 64);
  float zs = (float)zsum;

  const ushort* cr = cand + (size_t)row * 8;
  float best = 3.4e38f;
  int bidx = K_CB + 1;
  float2 bc = make_float2(0.f, 0.f);
#pragma unroll
  for (int j = 0; j < 8; ++j) {
    int cj = cr[j];
    float2 c = reinterpret_cast<const float2*>(cb)[(size_t)cj * 64 + lane];
    double p = (double)z.x * (double)c.x + (double)z.y * (double)c.y;
#pragma unroll
    for (int off = 32; off >= 1; off >>= 1) p += __shfl_xor(p, off, 64);
    float t = (float)(2.0 * p);       // fl32(2*cross)
    float u = zs - t;                 // fl32(ze_sq - t)
    float d = u + cbsq[cj];           // fl32(u + cb_sq)
    if (d < best || (d == best && cj < bidx)) { best = d; bidx = cj; bc = c; }
  }

  reinterpret_cast<float2*>(zq)[(size_t)row * 64 + lane] = bc;

  double dx = (double)z.x - (double)bc.x;
  double dy = (double)z.y - (double)bc.y;
  double l = dx * dx + dy * dy;
#pragma unroll
  for (int off = 32; off >= 1; off >>= 1) l += __shfl_xor(l, off, 64);

  __shared__ double sh[NROW_B];
  if (lane == 0) { idx_f[row] = (float)bidx; sh[w] = l; }
  __syncthreads();
  if (threadIdx.x == 0) partial[blockIdx.x] = sh[0] + sh[1] + sh[2] + sh[3];
}

__global__ __launch_bounds__(256) void finalize_kernel(
    const double* __restrict__ partial, float* __restrict__ out_loss) {
  double s = 0.0;
  for (int i = threadIdx.x; i < NBLK_B; i += 256) s += partial[i];
#pragma unroll
  for (int off = 32; off >= 1; off >>= 1) s += __shfl_down(s, off, 64);
  __shared__ double sh[4];
  int wv = threadIdx.x >> 6, lane = threadIdx.x & 63;
  if (lane == 0) sh[wv] = s;
  __syncthreads();
  if (threadIdx.x == 0) {
    double tot = sh[0] + sh[1] + sh[2] + sh[3];
    double mse = tot / (double)((size_t)N_TOT * C_DIM);
    *out_loss = (float)(1.75 * mse);  // 0.75*q_latent + e_latent, both == mse
  }
}

// ---------------------------------------------------------------------------
extern "C" void kernel_launch(void* const* d_in, const int* in_sizes, int n_in,
                              void* d_out, int out_size, void* d_ws, size_t ws_size,
                              hipStream_t stream) {
  const float* ze = (const float*)d_in[0];
  const float* cb = (const float*)d_in[1];

  float* out = (float*)d_out;
  float* zq = out;                                   // [N*C]
  float* out_loss = out + (size_t)N_TOT * C_DIM;     // [1]
  float* idx_f = out_loss + 1;                       // [N]

  float* cbsq = (float*)d_ws;                             // 4 KB @0
  float* cbsqb = (float*)((char*)d_ws + 4096);            // 4 KB
  ushort* cbs = (ushort*)((char*)d_ws + 8192);            // 256 KB (frag-ordered)
  ushort* cand = (ushort*)((char*)d_ws + 270336);         // 1 MB
  double* partial = (double*)((char*)d_ws + 1318912);     // 128 KB

  prep_kernel<<<68, 256, 0, stream>>>(cb, cbs, cbsq, cbsqb);
  dist_mfma_kernel<<<N_TOT / BN, 256, 0, stream>>>(ze, cbs, cbsqb, cand);
  rescore_kernel<<<NBLK_B, 256, 0, stream>>>(ze, cb, cbsq, cand, zq, idx_f, partial);
  finalize_kernel<<<1, 256, 0, stream>>>(partial, out_loss);
}